// Round 4
// baseline (173.824 us; speedup 1.0000x reference)
//
#include <hip/hip_runtime.h>
#include <hip/hip_bf16.h>

typedef __attribute__((ext_vector_type(8))) short short8;   // 8 x bf16 bits = 4 VGPRs
typedef __attribute__((ext_vector_type(4))) float f32x4;

#define NW 8            // waves per block
#define BPW 16          // batches per wave
#define BPB (NW * BPW)  // 128 batches per block

static __device__ __forceinline__ unsigned pk_bf16(float a, float b) {
    unsigned d;
    asm("v_cvt_pk_bf16_f32 %0, %1, %2" : "=v"(d) : "v"(a), "v"(b));
    return d;
}

// round-to-nearest-even bf16, returning the 16 bits
static __device__ __forceinline__ unsigned rne16(float x) {
    unsigned u = __float_as_uint(x);
    return (u + 0x7fffu + ((u >> 16) & 1u)) >> 16;
}
static __device__ __forceinline__ unsigned rne_bf16_pair(float x, float y) {
    return rne16(x) | (rne16(y) << 16);
}

static __device__ __forceinline__ short8 pack_frag(f32x4 a, f32x4 b) {
    union { unsigned u[4]; short8 s; } u;
    u.u[0] = pk_bf16(a.x, a.y);
    u.u[1] = pk_bf16(a.z, a.w);
    u.u[2] = pk_bf16(b.x, b.y);
    u.u[3] = pk_bf16(b.z, b.w);
    return u.s;
}

// Stage B-operand fragments of W^T (B[k][n] = W[n][k_off + k]) into LDS in
// fragment order: entry idx = (kt*nct + ct)*64 + lane; lane holds 8 bf16 with
// k = kt*32 + (lane>>4)*8 + j, n = ct*16 + (lane&15).
static __device__ __forceinline__ void stage_bfrags(const float* __restrict__ w,
                                                    int row_stride, int k_off, int nct,
                                                    short8* lds, int tid) {
    const int total = 4 * nct * 64;
    for (int idx = tid; idx < total; idx += NW * 64) {
        int lane = idx & 63;
        int ct = (idx >> 6) % nct;
        int kt = idx / (64 * nct);
        int n = ct * 16 + (lane & 15);
        int k = kt * 32 + (lane >> 4) * 8;
        const float* p = w + (size_t)n * row_stride + k_off + k;
        f32x4 a = *(const f32x4*)p;
        f32x4 b = *(const f32x4*)(p + 4);
        lds[idx] = pack_frag(a, b);
    }
}

// Same, but split each element into bf16 hi + bf16 residual (hi -> lds_hi, lo -> lds_lo).
static __device__ __forceinline__ void stage_bfrags_split(const float* __restrict__ w,
                                                          int row_stride, int nct,
                                                          short8* lds_hi, short8* lds_lo,
                                                          int tid) {
    const int total = 4 * nct * 64;
    for (int idx = tid; idx < total; idx += NW * 64) {
        int lane = idx & 63;
        int ct = (idx >> 6) % nct;
        int kt = idx / (64 * nct);
        int n = ct * 16 + (lane & 15);
        int k = kt * 32 + (lane >> 4) * 8;
        const float* p = w + (size_t)n * row_stride + k;
        f32x4 a = *(const f32x4*)p;
        f32x4 b = *(const f32x4*)(p + 4);
        float xs[8] = {a.x, a.y, a.z, a.w, b.x, b.y, b.z, b.w};
        union { unsigned u[4]; short8 s; } uh, ul;
#pragma unroll
        for (int q = 0; q < 4; ++q) {
            float x = xs[2 * q], y = xs[2 * q + 1];
            unsigned hx = rne16(x), hy = rne16(y);
            uh.u[q] = hx | (hy << 16);
            ul.u[q] = rne_bf16_pair(x - __uint_as_float(hx << 16),
                                    y - __uint_as_float(hy << 16));
        }
        lds_hi[idx] = uh.s;
        lds_lo[idx] = ul.s;
    }
}

__global__ __launch_bounds__(NW * 64, 3)
void mask_attn_fused(const float* __restrict__ value, const float* __restrict__ key,
                     const int* __restrict__ seq_len, const float* __restrict__ w1,
                     const float* __restrict__ b1, const float* __restrict__ w2,
                     const float* __restrict__ fcw, const float* __restrict__ fcb,
                     float* __restrict__ out, int B) {
    __shared__ short8 wlds[2048];  // 32 KiB: Wk -> Wv -> (fcw_hi | fcw_lo), time-shared

    const int tid = threadIdx.x;
    const int wave = tid >> 6;
    const int lane = tid & 63;
    const int g = lane >> 4;   // 0..3
    const int lo = lane & 15;  // 0..15

    const long long b0w = (long long)blockIdx.x * BPB + (long long)wave * BPW;
    long long vb = b0w + lo; if (vb > (long long)B - 1) vb = (long long)B - 1;

    // ---------- phase 1: Wk fragments -> LDS ----------
    stage_bfrags(w1, 2 * 128, 0, 8, wlds, tid);
    __syncthreads();

    // ---------- phase 2: HK = b1 + key @ Wk^T for this wave's 16 batches ----------
    // C/D layout: row = (lane>>4)*4 + reg (= batch index), col = ct*16 + (lane&15)
    unsigned hkp[8][2];
    {
        const float* kp = key + vb * 128 + g * 8;
        short8 af[4];
#pragma unroll
        for (int kt = 0; kt < 4; ++kt)
            af[kt] = pack_frag(*(const f32x4*)(kp + kt * 32), *(const f32x4*)(kp + kt * 32 + 4));
        f32x4 hk[8];
#pragma unroll
        for (int ct = 0; ct < 8; ++ct) {
            float bv = b1[ct * 16 + lo];
            hk[ct] = (f32x4){bv, bv, bv, bv};
        }
#pragma unroll
        for (int kt = 0; kt < 4; ++kt)
#pragma unroll
            for (int ct = 0; ct < 8; ++ct)
                hk[ct] = __builtin_amdgcn_mfma_f32_16x16x32_bf16(
                    af[kt], wlds[(kt * 8 + ct) * 64 + lane], hk[ct], 0, 0, 0);
#pragma unroll
        for (int ct = 0; ct < 8; ++ct) {
            hkp[ct][0] = rne_bf16_pair(hk[ct].x, hk[ct].y);
            hkp[ct][1] = rne_bf16_pair(hk[ct].z, hk[ct].w);
        }
    }
    __syncthreads();

    // ---------- phase 3: Wv fragments -> LDS ----------
    stage_bfrags(w1, 2 * 128, 128, 8, wlds, tid);
    __syncthreads();

    float w2v[8];
#pragma unroll
    for (int ct = 0; ct < 8; ++ct) w2v[ct] = w2[ct * 16 + lo];
    const int sq = seq_len[vb];  // valid positions: l <= sq (this lane's batch = lo row)

    // ---------- phase 4: fused per-l GEMM + logit extraction + FLASH softmax-sum ----
    // Lane (g,lo) owns batch (b0w+lo), dims d = kt*32 + g*8 + j. Value is read from
    // HBM exactly once; fp32 loads stay live through the MFMA/logit chain and feed
    // the weighted sum in fp32. Running-max online softmax (flash-style) reproduces
    // max-subtracted softmax semantics exactly, single-pass.
    float o[4][8];
#pragma unroll
    for (int kt = 0; kt < 4; ++kt)
#pragma unroll
        for (int j = 0; j < 8; ++j) o[kt][j] = 0.f;
    float s = 0.f, m = -3e38f;
    const float* ap = value + vb * (9 * 128) + g * 8;

#pragma unroll
    for (int l = 0; l < 9; ++l) {
        f32x4 va[8];  // fp32 value slice, kept live for the weighted sum
#pragma unroll
        for (int h = 0; h < 8; ++h)
            va[h] = *(const f32x4*)(ap + l * 128 + (h >> 1) * 32 + (h & 1) * 4);
        short8 af[4];
#pragma unroll
        for (int kt = 0; kt < 4; ++kt)
            af[kt] = pack_frag(va[2 * kt], va[2 * kt + 1]);
        f32x4 acc[8];
#pragma unroll
        for (int ct = 0; ct < 8; ++ct) {  // init C with hk (rows = same batches)
            acc[ct].x = __uint_as_float(hkp[ct][0] << 16);
            acc[ct].y = __uint_as_float(hkp[ct][0] & 0xffff0000u);
            acc[ct].z = __uint_as_float(hkp[ct][1] << 16);
            acc[ct].w = __uint_as_float(hkp[ct][1] & 0xffff0000u);
        }
#pragma unroll
        for (int kt = 0; kt < 4; ++kt)
#pragma unroll
            for (int ct = 0; ct < 8; ++ct)
                acc[ct] = __builtin_amdgcn_mfma_f32_16x16x32_bf16(
                    af[kt], wlds[(kt * 8 + ct) * 64 + lane], acc[ct], 0, 0, 0);
        // logit = sum_h relu(h) * w2[h]; per-lane partial over its 8 columns
        float p0 = 0.f, p1 = 0.f, p2 = 0.f, p3 = 0.f;
#pragma unroll
        for (int ct = 0; ct < 8; ++ct) {
            p0 += fmaxf(acc[ct].x, 0.f) * w2v[ct];
            p1 += fmaxf(acc[ct].y, 0.f) * w2v[ct];
            p2 += fmaxf(acc[ct].z, 0.f) * w2v[ct];
            p3 += fmaxf(acc[ct].w, 0.f) * w2v[ct];
        }
#pragma unroll
        for (int mm = 1; mm <= 8; mm <<= 1) {  // reduce across 16-lane column groups
            p0 += __shfl_xor(p0, mm);
            p1 += __shfl_xor(p1, mm);
            p2 += __shfl_xor(p2, mm);
            p3 += __shfl_xor(p3, mm);
        }
        // transpose: this lane keeps the logit of its own batch-row `lo`
        int sl = (lo >> 2) * 16;
        float t0 = __shfl(p0, sl), t1 = __shfl(p1, sl);
        float t2 = __shfl(p2, sl), t3 = __shfl(p3, sl);
        int r = lo & 3;
        float w = (r == 0) ? t0 : (r == 1) ? t1 : (r == 2) ? t2 : t3;

        // flash update (masked l: no-op)
        bool valid = (l <= sq);
        float mn = valid ? fmaxf(m, w) : m;
        float c = __expf(m - mn);              // ==1 when max unchanged; ==0 on first l
        float e = valid ? __expf(w - mn) : 0.f;
        s = s * c + e;
        m = mn;
#pragma unroll
        for (int kt = 0; kt < 4; ++kt) {
            o[kt][0] = o[kt][0] * c + e * va[2 * kt].x;
            o[kt][1] = o[kt][1] * c + e * va[2 * kt].y;
            o[kt][2] = o[kt][2] * c + e * va[2 * kt].z;
            o[kt][3] = o[kt][3] * c + e * va[2 * kt].w;
            o[kt][4] = o[kt][4] * c + e * va[2 * kt + 1].x;
            o[kt][5] = o[kt][5] * c + e * va[2 * kt + 1].y;
            o[kt][6] = o[kt][6] * c + e * va[2 * kt + 1].z;
            o[kt][7] = o[kt][7] * c + e * va[2 * kt + 1].w;
        }
    }

    // normalize; split O into bf16 hi+lo fc A-fragments (row = lo, k = kt*32+g*8+j)
    const float rs = 1.f / s;  // s>0 always: l=0 is always valid (sq >= 0)
    short8 afoh[4], afol[4];
#pragma unroll
    for (int kt = 0; kt < 4; ++kt) {
        union { unsigned u[4]; short8 v; } uh, ul;
#pragma unroll
        for (int p = 0; p < 4; ++p) {
            float x = o[kt][2 * p] * rs, y = o[kt][2 * p + 1] * rs;
            unsigned hx = rne16(x), hy = rne16(y);
            uh.u[p] = hx | (hy << 16);
            ul.u[p] = rne_bf16_pair(x - __uint_as_float(hx << 16),
                                    y - __uint_as_float(hy << 16));
        }
        afoh[kt] = uh.v;
        afol[kt] = ul.v;
    }

    __syncthreads();
    // ---------- phase 5: fcw hi/lo fragments -> LDS (hi: [0,1024), lo: [1024,2048)) --
    stage_bfrags_split(fcw, 128, 4, wlds, wlds + 1024, tid);
    __syncthreads();

    // ---------- phase 6: out = relu(O @ fcw^T + fcb), split-bf16 (3 cross terms) ----
    {
        f32x4 facc[4];
#pragma unroll
        for (int ct = 0; ct < 4; ++ct) {
            float fb = fcb[ct * 16 + lo];
            facc[ct] = (f32x4){fb, fb, fb, fb};
        }
#pragma unroll
        for (int kt = 0; kt < 4; ++kt)
#pragma unroll
            for (int ct = 0; ct < 4; ++ct) {
                short8 wh = wlds[(kt * 4 + ct) * 64 + lane];
                short8 wl = wlds[1024 + (kt * 4 + ct) * 64 + lane];
                facc[ct] = __builtin_amdgcn_mfma_f32_16x16x32_bf16(afoh[kt], wh, facc[ct], 0, 0, 0);
                facc[ct] = __builtin_amdgcn_mfma_f32_16x16x32_bf16(afol[kt], wh, facc[ct], 0, 0, 0);
                facc[ct] = __builtin_amdgcn_mfma_f32_16x16x32_bf16(afoh[kt], wl, facc[ct], 0, 0, 0);
            }
#pragma unroll
        for (int ct = 0; ct < 4; ++ct) {
            float v0 = fmaxf(facc[ct].x, 0.f), v1 = fmaxf(facc[ct].y, 0.f);
            float v2 = fmaxf(facc[ct].z, 0.f), v3 = fmaxf(facc[ct].w, 0.f);
            long long bo = b0w + g * 4;
            if (bo + 0 < B) out[(bo + 0) * 64 + ct * 16 + lo] = v0;
            if (bo + 1 < B) out[(bo + 1) * 64 + ct * 16 + lo] = v1;
            if (bo + 2 < B) out[(bo + 2) * 64 + ct * 16 + lo] = v2;
            if (bo + 3 < B) out[(bo + 3) * 64 + ct * 16 + lo] = v3;
        }
    }
}

extern "C" void kernel_launch(void* const* d_in, const int* in_sizes, int n_in,
                              void* d_out, int out_size, void* d_ws, size_t ws_size,
                              hipStream_t stream) {
    const float* value = (const float*)d_in[0];
    const float* key   = (const float*)d_in[1];
    const int*   seq   = (const int*)d_in[2];
    // d_in[3] = maxlen (unused; L == 9 fixed by reference)
    const float* w1    = (const float*)d_in[4];
    const float* b1    = (const float*)d_in[5];
    const float* w2    = (const float*)d_in[6];
    // d_in[7] = b2: softmax-invariant, dropped
    const float* fcw   = (const float*)d_in[8];
    const float* fcb   = (const float*)d_in[9];
    float* out = (float*)d_out;

    int B = in_sizes[1] / 128;
    int blocks = (B + BPB - 1) / BPB;
    mask_attn_fused<<<blocks, NW * 64, 0, stream>>>(value, key, seq, w1, b1, w2, fcw, fcb, out, B);
}

// Round 5
// 89.045 us; speedup vs baseline: 1.9521x; 1.9521x over previous
//
#include <hip/hip_runtime.h>
#include <hip/hip_bf16.h>

typedef __attribute__((ext_vector_type(8))) short short8;   // 8 x bf16 bits = 4 VGPRs
typedef __attribute__((ext_vector_type(4))) float f32x4;

#define NW 8            // waves per block
#define BPW 16          // batches per wave
#define BPB (NW * BPW)  // 128 batches per block

static __device__ __forceinline__ unsigned pk_bf16(float a, float b) {
    unsigned d;
    asm("v_cvt_pk_bf16_f32 %0, %1, %2" : "=v"(d) : "v"(a), "v"(b));
    return d;
}

// round-to-nearest-even bf16, returning the 16 bits
static __device__ __forceinline__ unsigned rne16(float x) {
    unsigned u = __float_as_uint(x);
    return (u + 0x7fffu + ((u >> 16) & 1u)) >> 16;
}
static __device__ __forceinline__ unsigned rne_bf16_pair(float x, float y) {
    return rne16(x) | (rne16(y) << 16);
}

static __device__ __forceinline__ short8 pack_frag(f32x4 a, f32x4 b) {
    union { unsigned u[4]; short8 s; } u;
    u.u[0] = pk_bf16(a.x, a.y);
    u.u[1] = pk_bf16(a.z, a.w);
    u.u[2] = pk_bf16(b.x, b.y);
    u.u[3] = pk_bf16(b.z, b.w);
    return u.s;
}

// Stage B-operand fragments of W^T (B[k][n] = W[n][k_off + k]) into LDS in
// fragment order: entry idx = (kt*nct + ct)*64 + lane; lane holds 8 bf16 with
// k = kt*32 + (lane>>4)*8 + j, n = ct*16 + (lane&15).
static __device__ __forceinline__ void stage_bfrags(const float* __restrict__ w,
                                                    int row_stride, int k_off, int nct,
                                                    short8* lds, int tid) {
    const int total = 4 * nct * 64;
    for (int idx = tid; idx < total; idx += NW * 64) {
        int lane = idx & 63;
        int ct = (idx >> 6) % nct;
        int kt = idx / (64 * nct);
        int n = ct * 16 + (lane & 15);
        int k = kt * 32 + (lane >> 4) * 8;
        const float* p = w + (size_t)n * row_stride + k_off + k;
        f32x4 a = *(const f32x4*)p;
        f32x4 b = *(const f32x4*)(p + 4);
        lds[idx] = pack_frag(a, b);
    }
}

// Same, but split each element into bf16 hi + bf16 residual (hi -> lds_hi, lo -> lds_lo).
static __device__ __forceinline__ void stage_bfrags_split(const float* __restrict__ w,
                                                          int row_stride, int nct,
                                                          short8* lds_hi, short8* lds_lo,
                                                          int tid) {
    const int total = 4 * nct * 64;
    for (int idx = tid; idx < total; idx += NW * 64) {
        int lane = idx & 63;
        int ct = (idx >> 6) % nct;
        int kt = idx / (64 * nct);
        int n = ct * 16 + (lane & 15);
        int k = kt * 32 + (lane >> 4) * 8;
        const float* p = w + (size_t)n * row_stride + k;
        f32x4 a = *(const f32x4*)p;
        f32x4 b = *(const f32x4*)(p + 4);
        float xs[8] = {a.x, a.y, a.z, a.w, b.x, b.y, b.z, b.w};
        union { unsigned u[4]; short8 s; } uh, ul;
#pragma unroll
        for (int q = 0; q < 4; ++q) {
            float x = xs[2 * q], y = xs[2 * q + 1];
            unsigned hx = rne16(x), hy = rne16(y);
            uh.u[q] = hx | (hy << 16);
            ul.u[q] = rne_bf16_pair(x - __uint_as_float(hx << 16),
                                    y - __uint_as_float(hy << 16));
        }
        lds_hi[idx] = uh.s;
        lds_lo[idx] = ul.s;
    }
}

// NOTE: measured on gfx950 (R1: (512,4)->64 VGPR, R4: (512,3)->84 VGPR): the
// 2nd __launch_bounds__ arg acts as CUDA-style min BLOCKS per CU. (512,2)
// -> 16 waves/CU -> 128-VGPR cap, which this kernel is sized to fit.
__global__ __launch_bounds__(NW * 64, 2)
void mask_attn_fused(const float* __restrict__ value, const float* __restrict__ key,
                     const int* __restrict__ seq_len, const float* __restrict__ w1,
                     const float* __restrict__ b1, const float* __restrict__ w2,
                     const float* __restrict__ fcw, const float* __restrict__ fcb,
                     float* __restrict__ out, int B) {
    __shared__ short8 wlds[2048];  // 32 KiB: Wk -> Wv -> (fcw_hi | fcw_lo), time-shared

    const int tid = threadIdx.x;
    const int wave = tid >> 6;
    const int lane = tid & 63;
    const int g = lane >> 4;   // 0..3
    const int lo = lane & 15;  // 0..15

    const long long b0w = (long long)blockIdx.x * BPB + (long long)wave * BPW;
    long long vb = b0w + lo; if (vb > (long long)B - 1) vb = (long long)B - 1;

    // ---------- phase 1: Wk fragments -> LDS ----------
    stage_bfrags(w1, 2 * 128, 0, 8, wlds, tid);
    __syncthreads();

    // ---------- phase 2: HK = b1 + key @ Wk^T for this wave's 16 batches ----------
    // C/D layout: row = (lane>>4)*4 + reg (= batch index), col = ct*16 + (lane&15)
    unsigned hkp[8][2];
    {
        const float* kp = key + vb * 128 + g * 8;
        short8 af[4];
#pragma unroll
        for (int kt = 0; kt < 4; ++kt)
            af[kt] = pack_frag(*(const f32x4*)(kp + kt * 32), *(const f32x4*)(kp + kt * 32 + 4));
#pragma unroll
        for (int ct = 0; ct < 8; ++ct) {
            float bv = b1[ct * 16 + lo];
            f32x4 hk = (f32x4){bv, bv, bv, bv};
#pragma unroll
            for (int kt = 0; kt < 4; ++kt)
                hk = __builtin_amdgcn_mfma_f32_16x16x32_bf16(
                    af[kt], wlds[(kt * 8 + ct) * 64 + lane], hk, 0, 0, 0);
            hkp[ct][0] = rne_bf16_pair(hk.x, hk.y);
            hkp[ct][1] = rne_bf16_pair(hk.z, hk.w);
        }
    }
    __syncthreads();

    // ---------- phase 3: Wv fragments -> LDS ----------
    stage_bfrags(w1, 2 * 128, 128, 8, wlds, tid);
    __syncthreads();

    float w2v[8];
#pragma unroll
    for (int ct = 0; ct < 8; ++ct) w2v[ct] = w2[ct * 16 + lo];
    const int sq = seq_len[vb];  // valid positions: l <= sq (this lane's batch = lo row)

    // ---------- phase 4: fused per-l GEMM + logit extraction + FLASH softmax-sum ----
    // Lane (g,lo) owns batch (b0w+lo), dims d = kt*32 + g*8 + j. Value is read from
    // HBM exactly once; fp32 loads stay live through the MFMA/logit chain and feed
    // the weighted sum in fp32. ct-outer MFMA chains keep only ONE f32x4 acc live
    // (B-frags re-read from LDS per use); l-loop NOT unrolled -> fits 128 VGPRs.
    float o[4][8];
#pragma unroll
    for (int kt = 0; kt < 4; ++kt)
#pragma unroll
        for (int j = 0; j < 8; ++j) o[kt][j] = 0.f;
    float s = 0.f, m = -3e38f;
    const float* ap = value + vb * (9 * 128) + g * 8;

#pragma unroll 1
    for (int l = 0; l < 9; ++l) {
        f32x4 va[8];  // fp32 value slice, kept live for the weighted sum
#pragma unroll
        for (int h = 0; h < 8; ++h)
            va[h] = *(const f32x4*)(ap + l * 128 + (h >> 1) * 32 + (h & 1) * 4);
        short8 af[4];
#pragma unroll
        for (int kt = 0; kt < 4; ++kt)
            af[kt] = pack_frag(va[2 * kt], va[2 * kt + 1]);

        // logit partials: one acc chain per ct, 4 regs live
        float p0 = 0.f, p1 = 0.f, p2 = 0.f, p3 = 0.f;
#pragma unroll
        for (int ct = 0; ct < 8; ++ct) {
            f32x4 acc;
            acc.x = __uint_as_float(hkp[ct][0] << 16);
            acc.y = __uint_as_float(hkp[ct][0] & 0xffff0000u);
            acc.z = __uint_as_float(hkp[ct][1] << 16);
            acc.w = __uint_as_float(hkp[ct][1] & 0xffff0000u);
#pragma unroll
            for (int kt = 0; kt < 4; ++kt)
                acc = __builtin_amdgcn_mfma_f32_16x16x32_bf16(
                    af[kt], wlds[(kt * 8 + ct) * 64 + lane], acc, 0, 0, 0);
            p0 += fmaxf(acc.x, 0.f) * w2v[ct];
            p1 += fmaxf(acc.y, 0.f) * w2v[ct];
            p2 += fmaxf(acc.z, 0.f) * w2v[ct];
            p3 += fmaxf(acc.w, 0.f) * w2v[ct];
        }
#pragma unroll
        for (int mm = 1; mm <= 8; mm <<= 1) {  // reduce across 16-lane column groups
            p0 += __shfl_xor(p0, mm);
            p1 += __shfl_xor(p1, mm);
            p2 += __shfl_xor(p2, mm);
            p3 += __shfl_xor(p3, mm);
        }
        // transpose: this lane keeps the logit of its own batch-row `lo`
        int sl = (lo >> 2) * 16;
        float t0 = __shfl(p0, sl), t1 = __shfl(p1, sl);
        float t2 = __shfl(p2, sl), t3 = __shfl(p3, sl);
        int r = lo & 3;
        float w = (r == 0) ? t0 : (r == 1) ? t1 : (r == 2) ? t2 : t3;

        // flash update (masked l: no-op)
        bool valid = (l <= sq);
        float mn = valid ? fmaxf(m, w) : m;
        float c = __expf(m - mn);              // ==1 when max unchanged; ==0 on first l
        float e = valid ? __expf(w - mn) : 0.f;
        s = s * c + e;
        m = mn;
#pragma unroll
        for (int kt = 0; kt < 4; ++kt) {
            o[kt][0] = o[kt][0] * c + e * va[2 * kt].x;
            o[kt][1] = o[kt][1] * c + e * va[2 * kt].y;
            o[kt][2] = o[kt][2] * c + e * va[2 * kt].z;
            o[kt][3] = o[kt][3] * c + e * va[2 * kt].w;
            o[kt][4] = o[kt][4] * c + e * va[2 * kt + 1].x;
            o[kt][5] = o[kt][5] * c + e * va[2 * kt + 1].y;
            o[kt][6] = o[kt][6] * c + e * va[2 * kt + 1].z;
            o[kt][7] = o[kt][7] * c + e * va[2 * kt + 1].w;
        }
    }

    // normalize; split O into bf16 hi+lo fc A-fragments (row = lo, k = kt*32+g*8+j)
    const float rs = 1.f / s;  // s>0 always: l=0 is always valid (sq >= 0)
    short8 afoh[4], afol[4];
#pragma unroll
    for (int kt = 0; kt < 4; ++kt) {
        union { unsigned u[4]; short8 v; } uh, ul;
#pragma unroll
        for (int p = 0; p < 4; ++p) {
            float x = o[kt][2 * p] * rs, y = o[kt][2 * p + 1] * rs;
            unsigned hx = rne16(x), hy = rne16(y);
            uh.u[p] = hx | (hy << 16);
            ul.u[p] = rne_bf16_pair(x - __uint_as_float(hx << 16),
                                    y - __uint_as_float(hy << 16));
        }
        afoh[kt] = uh.v;
        afol[kt] = ul.v;
    }

    __syncthreads();
    // ---------- phase 5: fcw hi/lo fragments -> LDS (hi: [0,1024), lo: [1024,2048)) --
    stage_bfrags_split(fcw, 128, 4, wlds, wlds + 1024, tid);
    __syncthreads();

    // ---------- phase 6: out = relu(O @ fcw^T + fcb), split-bf16 (3 cross terms) ----
    {
        f32x4 facc[4];
#pragma unroll
        for (int ct = 0; ct < 4; ++ct) {
            float fb = fcb[ct * 16 + lo];
            facc[ct] = (f32x4){fb, fb, fb, fb};
        }
#pragma unroll
        for (int kt = 0; kt < 4; ++kt)
#pragma unroll
            for (int ct = 0; ct < 4; ++ct) {
                short8 wh = wlds[(kt * 4 + ct) * 64 + lane];
                short8 wl = wlds[1024 + (kt * 4 + ct) * 64 + lane];
                facc[ct] = __builtin_amdgcn_mfma_f32_16x16x32_bf16(afoh[kt], wh, facc[ct], 0, 0, 0);
                facc[ct] = __builtin_amdgcn_mfma_f32_16x16x32_bf16(afol[kt], wh, facc[ct], 0, 0, 0);
                facc[ct] = __builtin_amdgcn_mfma_f32_16x16x32_bf16(afoh[kt], wl, facc[ct], 0, 0, 0);
            }
#pragma unroll
        for (int ct = 0; ct < 4; ++ct) {
            float v0 = fmaxf(facc[ct].x, 0.f), v1 = fmaxf(facc[ct].y, 0.f);
            float v2 = fmaxf(facc[ct].z, 0.f), v3 = fmaxf(facc[ct].w, 0.f);
            long long bo = b0w + g * 4;
            if (bo + 0 < B) out[(bo + 0) * 64 + ct * 16 + lo] = v0;
            if (bo + 1 < B) out[(bo + 1) * 64 + ct * 16 + lo] = v1;
            if (bo + 2 < B) out[(bo + 2) * 64 + ct * 16 + lo] = v2;
            if (bo + 3 < B) out[(bo + 3) * 64 + ct * 16 + lo] = v3;
        }
    }
}

extern "C" void kernel_launch(void* const* d_in, const int* in_sizes, int n_in,
                              void* d_out, int out_size, void* d_ws, size_t ws_size,
                              hipStream_t stream) {
    const float* value = (const float*)d_in[0];
    const float* key   = (const float*)d_in[1];
    const int*   seq   = (const int*)d_in[2];
    // d_in[3] = maxlen (unused; L == 9 fixed by reference)
    const float* w1    = (const float*)d_in[4];
    const float* b1    = (const float*)d_in[5];
    const float* w2    = (const float*)d_in[6];
    // d_in[7] = b2: softmax-invariant, dropped
    const float* fcw   = (const float*)d_in[8];
    const float* fcb   = (const float*)d_in[9];
    float* out = (float*)d_out;

    int B = in_sizes[1] / 128;
    int blocks = (B + BPB - 1) / BPB;
    mask_attn_fused<<<blocks, NW * 64, 0, stream>>>(value, key, seq, w1, b1, w2, fcw, fcb, out, B);
}